// Round 13
// baseline (438.371 us; speedup 1.0000x reference)
//
#include <hip/hip_runtime.h>

// ---------------------------------------------------------------------------
// WeightSharedBlock: B=4, N=1024, C=768, H=12, KS=7, DFF=3072
// Round 13: softmax_mix v3 — packed f32x4 math (v_pk_fma_f32), vectorized
// T-coefficient LDS reads, v_cvt_pk_bf16_f32 stores, rcp normalize.
// Rest identical to round 12 (validated, 438us).
// ---------------------------------------------------------------------------

typedef unsigned short u16;
typedef __bf16 bf16x8 __attribute__((ext_vector_type(8)));
typedef u16 u16x8 __attribute__((ext_vector_type(8)));
typedef float f32x4 __attribute__((ext_vector_type(4)));

using gvoid = __attribute__((address_space(1))) const void;
using lvoid = __attribute__((address_space(3))) void;
#define GLD16(GP, LP) __builtin_amdgcn_global_load_lds((gvoid*)(GP), (lvoid*)(LP), 16, 0, 0)

__device__ __forceinline__ u16 f2b(float f) {
  unsigned u = __float_as_uint(f);
  u = (u + 0x7FFFu + ((u >> 16) & 1u)) >> 16;
  return (u16)u;
}
__device__ __forceinline__ float b2f(u16 b) { return __uint_as_float(((unsigned)b) << 16); }
__device__ __forceinline__ float gelu_exact(float x) {
  return 0.5f * x * (1.f + erff(x * 0.70710678118654752f));
}
__device__ __forceinline__ unsigned pk2(float a, float b) {
  return (unsigned)f2b(a) | ((unsigned)f2b(b) << 16);
}
__device__ __forceinline__ unsigned cvtpk(float a, float b) {
  unsigned r;
  asm("v_cvt_pk_bf16_f32 %0, %1, %2" : "=v"(r) : "v"(a), "v"(b));
  return r;
}

// ---------------------------------------------------------------------------
// single combined weight cast (4 segments, float4 -> 4x bf16)
__global__ __launch_bounds__(256) void cast_all(const float* __restrict__ s0,
                                                const float* __restrict__ s1,
                                                const float* __restrict__ s2,
                                                const float* __restrict__ s3,
                                                u16* __restrict__ d0, u16* __restrict__ d1,
                                                u16* __restrict__ d2, u16* __restrict__ d3) {
  const int n0 = 1769472 / 4, n1 = 589824 / 4, n2 = 2359296 / 4;
  int j = blockIdx.x * 256 + threadIdx.x;
  const float* src;
  u16* dst;
  if (j < n0) { src = s0; dst = d0; }
  else if ((j -= n0) < n1) { src = s1; dst = d1; }
  else if ((j -= n1) < n2) { src = s2; dst = d2; }
  else { j -= n2; src = s3; dst = d3; }
  const float4 v = ((const float4*)src)[j];
  ushort4 o;
  o.x = f2b(v.x); o.y = f2b(v.y); o.z = f2b(v.z); o.w = f2b(v.w);
  ((ushort4*)dst)[j] = o;
}

// ---------------------------------------------------------------------------
// Row LayerNorm over 768 features. 256 threads/row, 3 elems/thread.
template <typename OutT>
__global__ __launch_bounds__(256) void ln_row(const float* __restrict__ x,
                                              const float* __restrict__ g,
                                              const float* __restrict__ be,
                                              OutT* __restrict__ out) {
  const long row = blockIdx.x;
  const float* xr = x + row * 768;
  OutT* yr = out + row * 768;
  const int tid = threadIdx.x;
  const int w = tid >> 6, lane = tid & 63;
  float v[3], s = 0.f, s2 = 0.f;
#pragma unroll
  for (int i = 0; i < 3; ++i) {
    v[i] = xr[tid + i * 256];
    s += v[i];
    s2 += v[i] * v[i];
  }
#pragma unroll
  for (int off = 32; off; off >>= 1) {
    s += __shfl_xor(s, off);
    s2 += __shfl_xor(s2, off);
  }
  __shared__ float red[8];
  if (lane == 0) { red[w] = s; red[w + 4] = s2; }
  __syncthreads();
  s = red[0] + red[1] + red[2] + red[3];
  s2 = red[4] + red[5] + red[6] + red[7];
  const float mu = s * (1.f / 768.f);
  const float var = s2 * (1.f / 768.f) - mu * mu;
  const float rstd = rsqrtf(var + 1e-5f);
#pragma unroll
  for (int i = 0; i < 3; ++i) {
    const int c = tid + i * 256;
    float y = (v[i] - mu) * rstd * g[c] + be[c];
    if constexpr (sizeof(OutT) == 2) yr[c] = f2b(y);
    else yr[c] = y;
  }
}

// ---------------------------------------------------------------------------
// bf16 GEMM: C[M,N] = act(A[M,K] @ B[N,K]^T + bias) (+res)
// TMxTN tile, BK=32, 4 waves (2x2 quadrants), double-buffered LDS,
// ONE barrier per K-step. SWAPPED mfma operands: C-col lives in the register
// index -> float4/b64 vector epilogue stores, float4 bias/res loads.
template <int TM, int TN, int ACT, bool HAS_RES, typename OutT>
__global__ __launch_bounds__(256) void gemm_bt(
    const u16* __restrict__ A, const u16* __restrict__ B, OutT* __restrict__ C,
    const float* __restrict__ bias, const float* __restrict__ res,
    int K, int lda, int ldb, int ldc, int ldr) {
  constexpr int WM = TM / 2, WN = TN / 2, MR = WM / 16, NR = WN / 16;
  __shared__ __align__(16) u16 As[2][TM * 32];
  __shared__ __align__(16) u16 Bs[2][TN * 32];
  const int tid = threadIdx.x;
  const int w = tid >> 6, lane = tid & 63;
  const int wr = w >> 1, wc = w & 1;
  const int l16 = lane & 15, lh = lane >> 4;
  const long rowA = (long)blockIdx.y * TM;
  const long colB = (long)blockIdx.x * TN;
  const int srow = tid >> 2;
  const int scol = (((tid & 3) ^ (srow & 3))) * 8;

  f32x4 acc[NR][MR];
#pragma unroll
  for (int n = 0; n < NR; ++n)
#pragma unroll
    for (int m = 0; m < MR; ++m) acc[n][m] = f32x4{0.f, 0.f, 0.f, 0.f};

  auto stage = [&](int buf, int k0) {
#pragma unroll
    for (int r = 0; r < TM / 64; ++r)
      GLD16(A + (rowA + r * 64 + srow) * (long)lda + k0 + scol, (char*)As[buf] + r * 4096 + w * 1024);
#pragma unroll
    for (int r = 0; r < TN / 64; ++r)
      GLD16(B + (colB + r * 64 + srow) * (long)ldb + k0 + scol, (char*)Bs[buf] + r * 4096 + w * 1024);
  };

  stage(0, 0);
  __syncthreads();
  const int nk = K >> 5;
  const int rx = (lh ^ (l16 & 3)) * 8;
  for (int t = 0; t < nk; ++t) {
    const int buf = t & 1;
    if (t + 1 < nk) stage(buf ^ 1, (t + 1) << 5);
    bf16x8 a[MR], bb[NR];
#pragma unroll
    for (int m = 0; m < MR; ++m)
      a[m] = *(const bf16x8*)&As[buf][(wr * WM + m * 16 + l16) * 32 + rx];
#pragma unroll
    for (int n = 0; n < NR; ++n)
      bb[n] = *(const bf16x8*)&Bs[buf][(wc * WN + n * 16 + l16) * 32 + rx];
#pragma unroll
    for (int n = 0; n < NR; ++n)
#pragma unroll
      for (int m = 0; m < MR; ++m)
        acc[n][m] = __builtin_amdgcn_mfma_f32_16x16x32_bf16(bb[n], a[m], acc[n][m], 0, 0, 0);
    __syncthreads();
  }

  // epilogue: lane holds 4 consecutive C-cols (register index r) for row l16
  const long row0 = rowA + wr * WM;
  const long col0 = colB + wc * WN;
#pragma unroll
  for (int m = 0; m < MR; ++m) {
    const long row = row0 + m * 16 + l16;
#pragma unroll
    for (int n = 0; n < NR; ++n) {
      const long colb = col0 + n * 16 + lh * 4;
      f32x4 v = acc[n][m];
      if (bias) {
        const float4 bv = *(const float4*)&bias[colb];
        v[0] += bv.x; v[1] += bv.y; v[2] += bv.z; v[3] += bv.w;
      }
      if (ACT == 1) {
#pragma unroll
        for (int r = 0; r < 4; ++r) v[r] = gelu_exact(v[r]);
      }
      if (HAS_RES) {
        const float4 rv = *(const float4*)&res[row * (long)ldr + colb];
        v[0] += rv.x; v[1] += rv.y; v[2] += rv.z; v[3] += rv.w;
      }
      if constexpr (sizeof(OutT) == 2) {
        uint2 d;
        d.x = pk2(v[0], v[1]);
        d.y = pk2(v[2], v[3]);
        *(uint2*)&C[row * (long)ldc + colb] = d;
      } else {
        float4 d = {v[0], v[1], v[2], v[3]};
        *(float4*)&C[row * (long)ldc + colb] = d;
      }
    }
  }
}

// ---------------------------------------------------------------------------
// Raw per-head scores: attn[b,h,n,m] = 0.125 * Q_h[n,:] . K_h[m,:]
// Tile 128m x 64n per (b,h); K=64 single-shot staging (24KB, one barrier).
// Swapped mfma (A=K, B=Q): lane holds 4 consecutive m -> b64 stores.
__global__ __launch_bounds__(256) void scores_raw(const u16* __restrict__ qkv,
                                                  u16* __restrict__ attn) {
  __shared__ __align__(16) u16 Ks[128 * 64];  // 16 KB [m][kd swz]
  __shared__ __align__(16) u16 Qs[64 * 64];   // 8 KB  [n][kd swz]
  const int tid = threadIdx.x;
  const int w = tid >> 6, lane = tid & 63;
  const int z = blockIdx.z, b = z / 12, h = z % 12;
  const int m0 = blockIdx.x * 128, n0 = blockIdx.y * 64;
  const int l16 = lane & 15, lh = lane >> 4;
  const int sr = tid >> 3, sc = tid & 7;
  const u16* Kb = qkv + ((long)(b << 10)) * 2304 + 768 + h * 64;
  const u16* Qb = qkv + ((long)(b << 10)) * 2304 + h * 64;
#pragma unroll
  for (int i = 0; i < 4; ++i) {
    const int r = i * 32 + sr;
    GLD16(Kb + (long)(m0 + r) * 2304 + (sc ^ (r & 7)) * 8, (char*)Ks + i * 4096 + w * 1024);
  }
#pragma unroll
  for (int i = 0; i < 2; ++i) {
    const int r = i * 32 + sr;
    GLD16(Qb + (long)(n0 + r) * 2304 + (sc ^ (r & 7)) * 8, (char*)Qs + i * 4096 + w * 1024);
  }
  __syncthreads();
  const int mb = (w & 1) * 64, nb = (w >> 1) * 32;
  f32x4 acc[2][4];
#pragma unroll
  for (int n = 0; n < 2; ++n)
#pragma unroll
    for (int m = 0; m < 4; ++m) acc[n][m] = f32x4{0.f, 0.f, 0.f, 0.f};
#pragma unroll
  for (int kk = 0; kk < 2; ++kk) {
    bf16x8 kf[4], qf[2];
    const int g4 = (kk << 2) | lh;
#pragma unroll
    for (int mf = 0; mf < 4; ++mf) {
      const int row = mb + mf * 16 + l16;
      kf[mf] = *(const bf16x8*)&Ks[row * 64 + (g4 ^ (row & 7)) * 8];
    }
#pragma unroll
    for (int nf = 0; nf < 2; ++nf) {
      const int row = nb + nf * 16 + l16;
      qf[nf] = *(const bf16x8*)&Qs[row * 64 + (g4 ^ (row & 7)) * 8];
    }
#pragma unroll
    for (int nf = 0; nf < 2; ++nf)
#pragma unroll
      for (int mf = 0; mf < 4; ++mf)
        acc[nf][mf] = __builtin_amdgcn_mfma_f32_16x16x32_bf16(kf[mf], qf[nf], acc[nf][mf], 0, 0, 0);
  }
  const long gbase = ((long)z << 20);
#pragma unroll
  for (int nf = 0; nf < 2; ++nf) {
    const int n = n0 + nb + nf * 16 + l16;
    u16* dst = attn + gbase + (long)n * 1024 + m0 + mb + lh * 4;
#pragma unroll
    for (int mf = 0; mf < 4; ++mf) {
      uint2 d;
      d.x = pk2(acc[nf][mf][0] * 0.125f, acc[nf][mf][1] * 0.125f);
      d.y = pk2(acc[nf][mf][2] * 0.125f, acc[nf][mf][3] * 0.125f);
      *(uint2*)(dst + mf * 16) = d;
    }
  }
}

// ---------------------------------------------------------------------------
// Fused mix-before + softmax + mix-after v3: block = (b, n) row; all 12 head
// rows in f32x4 registers (packed v_pk_fma math); Ts stored TRANSPOSED so
// mix-before reads T as b128 vectors; batched reductions (3 barriers);
// rcp normalize; v_cvt_pk_bf16_f32 stores.
__global__ __launch_bounds__(256) void softmax_mix(u16* __restrict__ attn,
                                                   const float* __restrict__ TbM,
                                                   const float* __restrict__ TgM) {
  const int bi = blockIdx.x >> 10;
  const int n = blockIdx.x & 1023;
  __shared__ __align__(16) float Tst[144];  // transposed: Tst[h*12+g] = Tb[g*12+h]
  __shared__ __align__(16) float Ta[144];   // natural: Ta[g*12+h]
  __shared__ float redm[4][12], reds[4][12];
  const int tid = threadIdx.x;
  const int w = tid >> 6, lane = tid & 63;
  if (tid < 144) {
    Tst[tid] = TbM[(tid % 12) * 12 + tid / 12];
    Ta[tid] = TgM[tid];
  }
  __syncthreads();
  const long base = (((long)bi * 12) << 20) + (long)n * 1024;
  // mix-before, h-interchanged: load raw[h], accumulate into all p[g]
  f32x4 p[12];
#pragma unroll
  for (int g = 0; g < 12; ++g) p[g] = f32x4{0.f, 0.f, 0.f, 0.f};
#pragma unroll
  for (int h = 0; h < 12; ++h) {
    const uint2 d = ((const uint2*)(attn + base + ((long)h << 20)))[tid];
    const f32x4 r = {b2f((u16)(d.x & 0xffff)), b2f((u16)(d.x >> 16)),
                     b2f((u16)(d.y & 0xffff)), b2f((u16)(d.y >> 16))};
    const f32x4 t0 = *(const f32x4*)&Tst[h * 12];
    const f32x4 t1 = *(const f32x4*)&Tst[h * 12 + 4];
    const f32x4 t2 = *(const f32x4*)&Tst[h * 12 + 8];
#pragma unroll
    for (int j = 0; j < 4; ++j) {
      p[j] += t0[j] * r;
      p[4 + j] += t1[j] * r;
      p[8 + j] += t2[j] * r;
    }
  }
  // batched max: wave-local shfl reductions for all 12 heads, ONE barrier
  float mx[12];
#pragma unroll
  for (int g = 0; g < 12; ++g) {
    mx[g] = fmaxf(fmaxf(p[g][0], p[g][1]), fmaxf(p[g][2], p[g][3]));
#pragma unroll
    for (int off = 32; off; off >>= 1) mx[g] = fmaxf(mx[g], __shfl_xor(mx[g], off));
  }
  if (lane == 0) {
#pragma unroll
    for (int g = 0; g < 12; ++g) redm[w][g] = mx[g];
  }
  __syncthreads();
  // exp + batched sum
  float sm[12];
#pragma unroll
  for (int g = 0; g < 12; ++g) {
    const float M = fmaxf(fmaxf(redm[0][g], redm[1][g]), fmaxf(redm[2][g], redm[3][g]));
#pragma unroll
    for (int i = 0; i < 4; ++i) p[g][i] = __expf(p[g][i] - M);
    sm[g] = (p[g][0] + p[g][1]) + (p[g][2] + p[g][3]);
#pragma unroll
    for (int off = 32; off; off >>= 1) sm[g] += __shfl_xor(sm[g], off);
  }
  if (lane == 0) {
#pragma unroll
    for (int g = 0; g < 12; ++g) reds[w][g] = sm[g];
  }
  __syncthreads();
#pragma unroll
  for (int g = 0; g < 12; ++g) {
    const float inv = __builtin_amdgcn_rcpf(
        (reds[0][g] + reds[1][g]) + (reds[2][g] + reds[3][g]));
    p[g] *= inv;
  }
  // mix-after (Ta rows are h-contiguous -> b128 reads) + cvt_pk stores
#pragma unroll
  for (int g = 0; g < 12; ++g) {
    const f32x4 t0 = *(const f32x4*)&Ta[g * 12];
    const f32x4 t1 = *(const f32x4*)&Ta[g * 12 + 4];
    const f32x4 t2 = *(const f32x4*)&Ta[g * 12 + 8];
    f32x4 o = f32x4{0.f, 0.f, 0.f, 0.f};
#pragma unroll
    for (int j = 0; j < 4; ++j) {
      o += t0[j] * p[j];
      o += t1[j] * p[4 + j];
      o += t2[j] * p[8 + j];
    }
    uint2 d;
    d.x = cvtpk(o[0], o[1]);
    d.y = cvtpk(o[2], o[3]);
    ((uint2*)(attn + base + ((long)g << 20)))[tid] = d;
  }
}

// ---------------------------------------------------------------------------
// AV: out[b,n,h*64+d] = sum_m attn[b,h,n,m] * V[b,m,h*64+d]
// 64-row tiles, 4 waves, double-buffered. SWAPPED mfma (a=V^T frag, b=P frag)
// -> lane holds 4 consecutive d -> b64 stores.
__global__ __launch_bounds__(256) void av_gemm(const u16* __restrict__ attn,
                                               const u16* __restrict__ qkv,
                                               u16* __restrict__ out) {
  __shared__ __align__(16) u16 As[2][64 * 32];
  __shared__ __align__(16) u16 Vt[2][64 * 40];
  const int tid = threadIdx.x;
  const int w = tid >> 6, lane = tid & 63;
  const int z = blockIdx.y, b = z / 12, h = z % 12;
  const u16* A = attn + ((long)z << 20);
  const u16* V = qkv + (long)b * 1024 * 2304 + 1536 + h * 64;
  const int rowA = blockIdx.x * 64;
  const int srow = tid >> 2;
  const int scol = (((tid & 3) ^ (srow & 3))) * 8;
  const int l16 = lane & 15, lh = lane >> 4;

  f32x4 acc[4];
#pragma unroll
  for (int n = 0; n < 4; ++n) acc[n] = f32x4{0.f, 0.f, 0.f, 0.f};

  auto stageA = [&](int buf, int k0) {
    GLD16(A + (long)(rowA + srow) * 1024 + k0 + scol, (char*)As[buf] + w * 1024);
  };
  auto stageV = [&](int buf, int k0) {
    u16x8 tmp;
#pragma unroll
    for (int j = 0; j < 8; ++j) tmp[j] = V[(long)(k0 + w * 8 + j) * 2304 + lane];
    *(u16x8*)&Vt[buf][lane * 40 + w * 8] = tmp;
  };

  stageA(0, 0);
  stageV(0, 0);
  __syncthreads();
  for (int t = 0; t < 32; ++t) {
    const int buf = t & 1;
    if (t < 31) { stageA(buf ^ 1, (t + 1) * 32); stageV(buf ^ 1, (t + 1) * 32); }
    const bf16x8 a = *(const bf16x8*)&As[buf][(w * 16 + l16) * 32 + (lh ^ (l16 & 3)) * 8];
    bf16x8 bv[4];
#pragma unroll
    for (int n = 0; n < 4; ++n)
      bv[n] = *(const bf16x8*)&Vt[buf][(n * 16 + l16) * 40 + lh * 8];
#pragma unroll
    for (int n = 0; n < 4; ++n)
      acc[n] = __builtin_amdgcn_mfma_f32_16x16x32_bf16(bv[n], a, acc[n], 0, 0, 0);
    __syncthreads();
  }
  // lane: token row = rowA + w*16 + l16; d-cols = df*16 + lh*4 + {0..3}
  const int tok = rowA + w * 16 + l16;
  u16* obase = out + ((long)(b << 10) + tok) * 768 + h * 64 + lh * 4;
#pragma unroll
  for (int df = 0; df < 4; ++df) {
    uint2 d;
    d.x = pk2(acc[df][0], acc[df][1]);
    d.y = pk2(acc[df][2], acc[df][3]);
    *(uint2*)(obase + df * 16) = d;
  }
}

// ---------------------------------------------------------------------------
// Depthwise conv1d over tokens, kernel 7, zero pad 3, float4 over channels.
__global__ __launch_bounds__(256) void dwconv4(const float* __restrict__ h2,
                                               const float* __restrict__ wgt,
                                               const float* __restrict__ bias,
                                               float* __restrict__ ct) {
  const int idx = blockIdx.x * 256 + threadIdx.x;  // 4*1024*192
  const int c4 = idx % 192;
  const int n = (idx / 192) % 1024;
  const int b = idx / (192 * 1024);
  const int c = c4 * 4;
  float4 acc = ((const float4*)bias)[c4];
#pragma unroll
  for (int t = 0; t < 7; ++t) {
    const int nn = n + t - 3;
    if (nn >= 0 && nn < 1024) {
      const float4 v = *(const float4*)&h2[((long)(b << 10) + nn) * 768 + c];
      acc.x += v.x * wgt[(c + 0) * 7 + t];
      acc.y += v.y * wgt[(c + 1) * 7 + t];
      acc.z += v.z * wgt[(c + 2) * 7 + t];
      acc.w += v.w * wgt[(c + 3) * 7 + t];
    }
  }
  ((float4*)ct)[idx] = acc;
}

// ---------------------------------------------------------------------------
extern "C" void kernel_launch(void* const* d_in, const int* in_sizes, int n_in,
                              void* d_out, int out_size, void* d_ws, size_t ws_size,
                              hipStream_t stream) {
  const float* x      = (const float*)d_in[0];
  const float* w_qkv  = (const float*)d_in[1];
  const float* b_qkv  = (const float*)d_in[2];
  const float* w_proj = (const float*)d_in[3];
  const float* b_proj = (const float*)d_in[4];
  const float* w_fc1  = (const float*)d_in[5];
  const float* b_fc1  = (const float*)d_in[6];
  const float* w_fc2  = (const float*)d_in[7];
  const float* b_fc2  = (const float*)d_in[8];
  const float* t_bef  = (const float*)d_in[9];
  const float* t_aft  = (const float*)d_in[10];
  const float* g1     = (const float*)d_in[11];
  const float* be1    = (const float*)d_in[12];
  const float* g2     = (const float*)d_in[13];
  const float* be2    = (const float*)d_in[14];
  const float* dw_w   = (const float*)d_in[15];
  const float* dw_b   = (const float*)d_in[16];
  const float* gm     = (const float*)d_in[17];
  const float* bm     = (const float*)d_in[18];
  float* out = (float*)d_out;

  char* wsp = (char*)d_ws;
  size_t off = 0;
  auto alloc = [&](size_t bytes) {
    char* r = wsp + off;
    off += (bytes + 255) & ~(size_t)255;
    return r;
  };
  u16* wqkv_b  = (u16*)alloc((size_t)2304 * 768 * 2);
  u16* wproj_b = (u16*)alloc((size_t)768 * 768 * 2);
  u16* wfc1_b  = (u16*)alloc((size_t)3072 * 768 * 2);
  u16* wfc2_b  = (u16*)alloc((size_t)768 * 3072 * 2);
  u16* h1      = (u16*)alloc((size_t)4096 * 768 * 2);   // LN1 out; dead after QKV
  u16* attn_out = h1;                                   // overlay
  u16* qkvb    = (u16*)alloc((size_t)4096 * 2304 * 2);
  char* attn_region = alloc((size_t)48 * 1024 * 1024 * 2);
  u16* attn = (u16*)attn_region;                        // dead after av_gemm
  size_t ro = 0;
  auto ralloc = [&](size_t bytes) {
    char* r = attn_region + ro;
    ro += (bytes + 255) & ~(size_t)255;
    return r;
  };
  float* x2   = (float*)ralloc((size_t)4096 * 768 * 4);
  float* h2   = (float*)ralloc((size_t)4096 * 768 * 4);
  float* ct   = (float*)ralloc((size_t)4096 * 768 * 4);
  u16*   hm   = (u16*)ralloc((size_t)4096 * 768 * 2);
  u16*   fc1o = (u16*)ralloc((size_t)4096 * 3072 * 2);
  (void)ws_size; (void)n_in; (void)in_sizes; (void)out_size;

  // weight casts (one kernel)
  cast_all<<<6912, 256, 0, stream>>>(w_qkv, w_proj, w_fc1, w_fc2,
                                     wqkv_b, wproj_b, wfc1_b, wfc2_b);
  // LN1
  ln_row<u16><<<4096, 256, 0, stream>>>(x, g1, be1, h1);
  // QKV: [4096,768] @ [2304,768]^T -> [4096,2304]
  gemm_bt<128, 64, 0, false, u16><<<dim3(36, 32), 256, 0, stream>>>(
      h1, wqkv_b, qkvb, b_qkv, nullptr, 768, 768, 768, 2304, 0);
  // raw per-head scaled scores -> attn
  scores_raw<<<dim3(8, 16, 48), 256, 0, stream>>>(qkvb, attn);
  // fused mix-before + softmax + mix-after (in-place)
  softmax_mix<<<4096, 256, 0, stream>>>(attn, t_bef, t_aft);
  // AV
  av_gemm<<<dim3(16, 48), 256, 0, stream>>>(attn, qkvb, attn_out);
  // proj + residual -> x2 (fp32)
  gemm_bt<128, 64, 0, true, float><<<dim3(12, 32), 256, 0, stream>>>(
      attn_out, wproj_b, x2, b_proj, x, 768, 768, 768, 768, 768);
  // LN2 -> h2
  ln_row<float><<<4096, 256, 0, stream>>>(x2, g2, be2, h2);
  // depthwise conv + bias -> ct
  dwconv4<<<3072, 256, 0, stream>>>(h2, dw_w, dw_b, ct);
  // LN mid -> hm (bf16)
  ln_row<u16><<<4096, 256, 0, stream>>>(ct, gm, bm, hm);
  // fc1 + GELU -> fc1o
  gemm_bt<128, 64, 1, false, u16><<<dim3(48, 32), 256, 0, stream>>>(
      hm, wfc1_b, fc1o, b_fc1, nullptr, 768, 768, 768, 3072, 0);
  // fc2 + residual -> out
  gemm_bt<128, 64, 0, true, float><<<dim3(12, 32), 256, 0, stream>>>(
      fc1o, wfc2_b, out, b_fc2, x2, 3072, 3072, 3072, 768, 768);
}

// Round 15
// 425.013 us; speedup vs baseline: 1.0314x; 1.0314x over previous
//
#include <hip/hip_runtime.h>

// ---------------------------------------------------------------------------
// WeightSharedBlock: B=4, N=1024, C=768, H=12, KS=7, DFF=3072
// Round 14 resubmit: QKV & fc1 GEMMs -> 128x128 tiles (32 MFMA/barrier);
// av_gemm -> 128-row tiles (8 MFMA/barrier). softmax_mix v3 & rest identical
// to round 13 (validated, 438us).
// ---------------------------------------------------------------------------

typedef unsigned short u16;
typedef __bf16 bf16x8 __attribute__((ext_vector_type(8)));
typedef u16 u16x8 __attribute__((ext_vector_type(8)));
typedef float f32x4 __attribute__((ext_vector_type(4)));

using gvoid = __attribute__((address_space(1))) const void;
using lvoid = __attribute__((address_space(3))) void;
#define GLD16(GP, LP) __builtin_amdgcn_global_load_lds((gvoid*)(GP), (lvoid*)(LP), 16, 0, 0)

__device__ __forceinline__ u16 f2b(float f) {
  unsigned u = __float_as_uint(f);
  u = (u + 0x7FFFu + ((u >> 16) & 1u)) >> 16;
  return (u16)u;
}
__device__ __forceinline__ float b2f(u16 b) { return __uint_as_float(((unsigned)b) << 16); }
__device__ __forceinline__ float gelu_exact(float x) {
  return 0.5f * x * (1.f + erff(x * 0.70710678118654752f));
}
__device__ __forceinline__ unsigned pk2(float a, float b) {
  return (unsigned)f2b(a) | ((unsigned)f2b(b) << 16);
}
__device__ __forceinline__ unsigned cvtpk(float a, float b) {
  unsigned r;
  asm("v_cvt_pk_bf16_f32 %0, %1, %2" : "=v"(r) : "v"(a), "v"(b));
  return r;
}

// ---------------------------------------------------------------------------
// single combined weight cast (4 segments, float4 -> 4x bf16)
__global__ __launch_bounds__(256) void cast_all(const float* __restrict__ s0,
                                                const float* __restrict__ s1,
                                                const float* __restrict__ s2,
                                                const float* __restrict__ s3,
                                                u16* __restrict__ d0, u16* __restrict__ d1,
                                                u16* __restrict__ d2, u16* __restrict__ d3) {
  const int n0 = 1769472 / 4, n1 = 589824 / 4, n2 = 2359296 / 4;
  int j = blockIdx.x * 256 + threadIdx.x;
  const float* src;
  u16* dst;
  if (j < n0) { src = s0; dst = d0; }
  else if ((j -= n0) < n1) { src = s1; dst = d1; }
  else if ((j -= n1) < n2) { src = s2; dst = d2; }
  else { j -= n2; src = s3; dst = d3; }
  const float4 v = ((const float4*)src)[j];
  ushort4 o;
  o.x = f2b(v.x); o.y = f2b(v.y); o.z = f2b(v.z); o.w = f2b(v.w);
  ((ushort4*)dst)[j] = o;
}

// ---------------------------------------------------------------------------
// Row LayerNorm over 768 features. 256 threads/row, 3 elems/thread.
template <typename OutT>
__global__ __launch_bounds__(256) void ln_row(const float* __restrict__ x,
                                              const float* __restrict__ g,
                                              const float* __restrict__ be,
                                              OutT* __restrict__ out) {
  const long row = blockIdx.x;
  const float* xr = x + row * 768;
  OutT* yr = out + row * 768;
  const int tid = threadIdx.x;
  const int w = tid >> 6, lane = tid & 63;
  float v[3], s = 0.f, s2 = 0.f;
#pragma unroll
  for (int i = 0; i < 3; ++i) {
    v[i] = xr[tid + i * 256];
    s += v[i];
    s2 += v[i] * v[i];
  }
#pragma unroll
  for (int off = 32; off; off >>= 1) {
    s += __shfl_xor(s, off);
    s2 += __shfl_xor(s2, off);
  }
  __shared__ float red[8];
  if (lane == 0) { red[w] = s; red[w + 4] = s2; }
  __syncthreads();
  s = red[0] + red[1] + red[2] + red[3];
  s2 = red[4] + red[5] + red[6] + red[7];
  const float mu = s * (1.f / 768.f);
  const float var = s2 * (1.f / 768.f) - mu * mu;
  const float rstd = rsqrtf(var + 1e-5f);
#pragma unroll
  for (int i = 0; i < 3; ++i) {
    const int c = tid + i * 256;
    float y = (v[i] - mu) * rstd * g[c] + be[c];
    if constexpr (sizeof(OutT) == 2) yr[c] = f2b(y);
    else yr[c] = y;
  }
}

// ---------------------------------------------------------------------------
// bf16 GEMM: C[M,N] = act(A[M,K] @ B[N,K]^T + bias) (+res)
// TMxTN tile, BK=32, 4 waves (2x2 quadrants), double-buffered LDS,
// ONE barrier per K-step. SWAPPED mfma operands: C-col lives in the register
// index -> float4/b64 vector epilogue stores, float4 bias/res loads.
template <int TM, int TN, int ACT, bool HAS_RES, typename OutT>
__global__ __launch_bounds__(256) void gemm_bt(
    const u16* __restrict__ A, const u16* __restrict__ B, OutT* __restrict__ C,
    const float* __restrict__ bias, const float* __restrict__ res,
    int K, int lda, int ldb, int ldc, int ldr) {
  constexpr int WM = TM / 2, WN = TN / 2, MR = WM / 16, NR = WN / 16;
  __shared__ __align__(16) u16 As[2][TM * 32];
  __shared__ __align__(16) u16 Bs[2][TN * 32];
  const int tid = threadIdx.x;
  const int w = tid >> 6, lane = tid & 63;
  const int wr = w >> 1, wc = w & 1;
  const int l16 = lane & 15, lh = lane >> 4;
  const long rowA = (long)blockIdx.y * TM;
  const long colB = (long)blockIdx.x * TN;
  const int srow = tid >> 2;
  const int scol = (((tid & 3) ^ (srow & 3))) * 8;

  f32x4 acc[NR][MR];
#pragma unroll
  for (int n = 0; n < NR; ++n)
#pragma unroll
    for (int m = 0; m < MR; ++m) acc[n][m] = f32x4{0.f, 0.f, 0.f, 0.f};

  auto stage = [&](int buf, int k0) {
#pragma unroll
    for (int r = 0; r < TM / 64; ++r)
      GLD16(A + (rowA + r * 64 + srow) * (long)lda + k0 + scol, (char*)As[buf] + r * 4096 + w * 1024);
#pragma unroll
    for (int r = 0; r < TN / 64; ++r)
      GLD16(B + (colB + r * 64 + srow) * (long)ldb + k0 + scol, (char*)Bs[buf] + r * 4096 + w * 1024);
  };

  stage(0, 0);
  __syncthreads();
  const int nk = K >> 5;
  const int rx = (lh ^ (l16 & 3)) * 8;
  for (int t = 0; t < nk; ++t) {
    const int buf = t & 1;
    if (t + 1 < nk) stage(buf ^ 1, (t + 1) << 5);
    bf16x8 a[MR], bb[NR];
#pragma unroll
    for (int m = 0; m < MR; ++m)
      a[m] = *(const bf16x8*)&As[buf][(wr * WM + m * 16 + l16) * 32 + rx];
#pragma unroll
    for (int n = 0; n < NR; ++n)
      bb[n] = *(const bf16x8*)&Bs[buf][(wc * WN + n * 16 + l16) * 32 + rx];
#pragma unroll
    for (int n = 0; n < NR; ++n)
#pragma unroll
      for (int m = 0; m < MR; ++m)
        acc[n][m] = __builtin_amdgcn_mfma_f32_16x16x32_bf16(bb[n], a[m], acc[n][m], 0, 0, 0);
    __syncthreads();
  }

  // epilogue: lane holds 4 consecutive C-cols (register index r) for row l16
  const long row0 = rowA + wr * WM;
  const long col0 = colB + wc * WN;
#pragma unroll
  for (int m = 0; m < MR; ++m) {
    const long row = row0 + m * 16 + l16;
#pragma unroll
    for (int n = 0; n < NR; ++n) {
      const long colb = col0 + n * 16 + lh * 4;
      f32x4 v = acc[n][m];
      if (bias) {
        const float4 bv = *(const float4*)&bias[colb];
        v[0] += bv.x; v[1] += bv.y; v[2] += bv.z; v[3] += bv.w;
      }
      if (ACT == 1) {
#pragma unroll
        for (int r = 0; r < 4; ++r) v[r] = gelu_exact(v[r]);
      }
      if (HAS_RES) {
        const float4 rv = *(const float4*)&res[row * (long)ldr + colb];
        v[0] += rv.x; v[1] += rv.y; v[2] += rv.z; v[3] += rv.w;
      }
      if constexpr (sizeof(OutT) == 2) {
        uint2 d;
        d.x = pk2(v[0], v[1]);
        d.y = pk2(v[2], v[3]);
        *(uint2*)&C[row * (long)ldc + colb] = d;
      } else {
        float4 d = {v[0], v[1], v[2], v[3]};
        *(float4*)&C[row * (long)ldc + colb] = d;
      }
    }
  }
}

// ---------------------------------------------------------------------------
// Raw per-head scores: attn[b,h,n,m] = 0.125 * Q_h[n,:] . K_h[m,:]
// Tile 128m x 64n per (b,h); K=64 single-shot staging (24KB, one barrier).
// Swapped mfma (A=K, B=Q): lane holds 4 consecutive m -> b64 stores.
__global__ __launch_bounds__(256) void scores_raw(const u16* __restrict__ qkv,
                                                  u16* __restrict__ attn) {
  __shared__ __align__(16) u16 Ks[128 * 64];  // 16 KB [m][kd swz]
  __shared__ __align__(16) u16 Qs[64 * 64];   // 8 KB  [n][kd swz]
  const int tid = threadIdx.x;
  const int w = tid >> 6, lane = tid & 63;
  const int z = blockIdx.z, b = z / 12, h = z % 12;
  const int m0 = blockIdx.x * 128, n0 = blockIdx.y * 64;
  const int l16 = lane & 15, lh = lane >> 4;
  const int sr = tid >> 3, sc = tid & 7;
  const u16* Kb = qkv + ((long)(b << 10)) * 2304 + 768 + h * 64;
  const u16* Qb = qkv + ((long)(b << 10)) * 2304 + h * 64;
#pragma unroll
  for (int i = 0; i < 4; ++i) {
    const int r = i * 32 + sr;
    GLD16(Kb + (long)(m0 + r) * 2304 + (sc ^ (r & 7)) * 8, (char*)Ks + i * 4096 + w * 1024);
  }
#pragma unroll
  for (int i = 0; i < 2; ++i) {
    const int r = i * 32 + sr;
    GLD16(Qb + (long)(n0 + r) * 2304 + (sc ^ (r & 7)) * 8, (char*)Qs + i * 4096 + w * 1024);
  }
  __syncthreads();
  const int mb = (w & 1) * 64, nb = (w >> 1) * 32;
  f32x4 acc[2][4];
#pragma unroll
  for (int n = 0; n < 2; ++n)
#pragma unroll
    for (int m = 0; m < 4; ++m) acc[n][m] = f32x4{0.f, 0.f, 0.f, 0.f};
#pragma unroll
  for (int kk = 0; kk < 2; ++kk) {
    bf16x8 kf[4], qf[2];
    const int g4 = (kk << 2) | lh;
#pragma unroll
    for (int mf = 0; mf < 4; ++mf) {
      const int row = mb + mf * 16 + l16;
      kf[mf] = *(const bf16x8*)&Ks[row * 64 + (g4 ^ (row & 7)) * 8];
    }
#pragma unroll
    for (int nf = 0; nf < 2; ++nf) {
      const int row = nb + nf * 16 + l16;
      qf[nf] = *(const bf16x8*)&Qs[row * 64 + (g4 ^ (row & 7)) * 8];
    }
#pragma unroll
    for (int nf = 0; nf < 2; ++nf)
#pragma unroll
      for (int mf = 0; mf < 4; ++mf)
        acc[nf][mf] = __builtin_amdgcn_mfma_f32_16x16x32_bf16(kf[mf], qf[nf], acc[nf][mf], 0, 0, 0);
  }
  const long gbase = ((long)z << 20);
#pragma unroll
  for (int nf = 0; nf < 2; ++nf) {
    const int n = n0 + nb + nf * 16 + l16;
    u16* dst = attn + gbase + (long)n * 1024 + m0 + mb + lh * 4;
#pragma unroll
    for (int mf = 0; mf < 4; ++mf) {
      uint2 d;
      d.x = pk2(acc[nf][mf][0] * 0.125f, acc[nf][mf][1] * 0.125f);
      d.y = pk2(acc[nf][mf][2] * 0.125f, acc[nf][mf][3] * 0.125f);
      *(uint2*)(dst + mf * 16) = d;
    }
  }
}

// ---------------------------------------------------------------------------
// Fused mix-before + softmax + mix-after v3: block = (b, n) row; all 12 head
// rows in f32x4 registers (packed v_pk_fma math); Ts stored TRANSPOSED so
// mix-before reads T as b128 vectors; batched reductions (3 barriers);
// rcp normalize; v_cvt_pk_bf16_f32 stores.
__global__ __launch_bounds__(256) void softmax_mix(u16* __restrict__ attn,
                                                   const float* __restrict__ TbM,
                                                   const float* __restrict__ TgM) {
  const int bi = blockIdx.x >> 10;
  const int n = blockIdx.x & 1023;
  __shared__ __align__(16) float Tst[144];  // transposed: Tst[h*12+g] = Tb[g*12+h]
  __shared__ __align__(16) float Ta[144];   // natural: Ta[g*12+h]
  __shared__ float redm[4][12], reds[4][12];
  const int tid = threadIdx.x;
  const int w = tid >> 6, lane = tid & 63;
  if (tid < 144) {
    Tst[tid] = TbM[(tid % 12) * 12 + tid / 12];
    Ta[tid] = TgM[tid];
  }
  __syncthreads();
  const long base = (((long)bi * 12) << 20) + (long)n * 1024;
  // mix-before, h-interchanged: load raw[h], accumulate into all p[g]
  f32x4 p[12];
#pragma unroll
  for (int g = 0; g < 12; ++g) p[g] = f32x4{0.f, 0.f, 0.f, 0.f};
#pragma unroll
  for (int h = 0; h < 12; ++h) {
    const uint2 d = ((const uint2*)(attn + base + ((long)h << 20)))[tid];
    const f32x4 r = {b2f((u16)(d.x & 0xffff)), b2f((u16)(d.x >> 16)),
                     b2f((u16)(d.y & 0xffff)), b2f((u16)(d.y >> 16))};
    const f32x4 t0 = *(const f32x4*)&Tst[h * 12];
    const f32x4 t1 = *(const f32x4*)&Tst[h * 12 + 4];
    const f32x4 t2 = *(const f32x4*)&Tst[h * 12 + 8];
#pragma unroll
    for (int j = 0; j < 4; ++j) {
      p[j] += t0[j] * r;
      p[4 + j] += t1[j] * r;
      p[8 + j] += t2[j] * r;
    }
  }
  // batched max: wave-local shfl reductions for all 12 heads, ONE barrier
  float mx[12];
#pragma unroll
  for (int g = 0; g < 12; ++g) {
    mx[g] = fmaxf(fmaxf(p[g][0], p[g][1]), fmaxf(p[g][2], p[g][3]));
#pragma unroll
    for (int off = 32; off; off >>= 1) mx[g] = fmaxf(mx[g], __shfl_xor(mx[g], off));
  }
  if (lane == 0) {
#pragma unroll
    for (int g = 0; g < 12; ++g) redm[w][g] = mx[g];
  }
  __syncthreads();
  // exp + batched sum
  float sm[12];
#pragma unroll
  for (int g = 0; g < 12; ++g) {
    const float M = fmaxf(fmaxf(redm[0][g], redm[1][g]), fmaxf(redm[2][g], redm[3][g]));
#pragma unroll
    for (int i = 0; i < 4; ++i) p[g][i] = __expf(p[g][i] - M);
    sm[g] = (p[g][0] + p[g][1]) + (p[g][2] + p[g][3]);
#pragma unroll
    for (int off = 32; off; off >>= 1) sm[g] += __shfl_xor(sm[g], off);
  }
  if (lane == 0) {
#pragma unroll
    for (int g = 0; g < 12; ++g) reds[w][g] = sm[g];
  }
  __syncthreads();
#pragma unroll
  for (int g = 0; g < 12; ++g) {
    const float inv = __builtin_amdgcn_rcpf(
        (reds[0][g] + reds[1][g]) + (reds[2][g] + reds[3][g]));
    p[g] *= inv;
  }
  // mix-after (Ta rows are h-contiguous -> b128 reads) + cvt_pk stores
#pragma unroll
  for (int g = 0; g < 12; ++g) {
    const f32x4 t0 = *(const f32x4*)&Ta[g * 12];
    const f32x4 t1 = *(const f32x4*)&Ta[g * 12 + 4];
    const f32x4 t2 = *(const f32x4*)&Ta[g * 12 + 8];
    f32x4 o = f32x4{0.f, 0.f, 0.f, 0.f};
#pragma unroll
    for (int j = 0; j < 4; ++j) {
      o += t0[j] * p[j];
      o += t1[j] * p[4 + j];
      o += t2[j] * p[8 + j];
    }
    uint2 d;
    d.x = cvtpk(o[0], o[1]);
    d.y = cvtpk(o[2], o[3]);
    ((uint2*)(attn + base + ((long)g << 20)))[tid] = d;
  }
}

// ---------------------------------------------------------------------------
// AV: out[b,n,h*64+d] = sum_m attn[b,h,n,m] * V[b,m,h*64+d]
// 128-row tiles, 4 waves (32 rows each, 2 row-frags), double-buffered.
// SWAPPED mfma -> lane holds 4 consecutive d -> b64 stores.
__global__ __launch_bounds__(256) void av_gemm(const u16* __restrict__ attn,
                                               const u16* __restrict__ qkv,
                                               u16* __restrict__ out) {
  __shared__ __align__(16) u16 As[2][128 * 32];  // 8 KB/buf
  __shared__ __align__(16) u16 Vt[2][64 * 40];
  const int tid = threadIdx.x;
  const int w = tid >> 6, lane = tid & 63;
  const int z = blockIdx.y, b = z / 12, h = z % 12;
  const u16* A = attn + ((long)z << 20);
  const u16* V = qkv + (long)b * 1024 * 2304 + 1536 + h * 64;
  const int rowA = blockIdx.x * 128;
  const int srow = tid >> 2;
  const int scol = (((tid & 3) ^ (srow & 3))) * 8;
  const int l16 = lane & 15, lh = lane >> 4;

  f32x4 acc[2][4];
#pragma unroll
  for (int m = 0; m < 2; ++m)
#pragma unroll
    for (int n = 0; n < 4; ++n) acc[m][n] = f32x4{0.f, 0.f, 0.f, 0.f};

  auto stageA = [&](int buf, int k0) {
#pragma unroll
    for (int r = 0; r < 2; ++r)
      GLD16(A + (long)(rowA + r * 64 + srow) * 1024 + k0 + scol,
            (char*)As[buf] + r * 4096 + w * 1024);
  };
  auto stageV = [&](int buf, int k0) {
    u16x8 tmp;
#pragma unroll
    for (int j = 0; j < 8; ++j) tmp[j] = V[(long)(k0 + w * 8 + j) * 2304 + lane];
    *(u16x8*)&Vt[buf][lane * 40 + w * 8] = tmp;
  };

  stageA(0, 0);
  stageV(0, 0);
  __syncthreads();
  for (int t = 0; t < 32; ++t) {
    const int buf = t & 1;
    if (t < 31) { stageA(buf ^ 1, (t + 1) * 32); stageV(buf ^ 1, (t + 1) * 32); }
    bf16x8 a[2];
#pragma unroll
    for (int mf = 0; mf < 2; ++mf)
      a[mf] = *(const bf16x8*)&As[buf][(w * 32 + mf * 16 + l16) * 32 + (lh ^ (l16 & 3)) * 8];
    bf16x8 bv[4];
#pragma unroll
    for (int n = 0; n < 4; ++n)
      bv[n] = *(const bf16x8*)&Vt[buf][(n * 16 + l16) * 40 + lh * 8];
#pragma unroll
    for (int mf = 0; mf < 2; ++mf)
#pragma unroll
      for (int n = 0; n < 4; ++n)
        acc[mf][n] = __builtin_amdgcn_mfma_f32_16x16x32_bf16(bv[n], a[mf], acc[mf][n], 0, 0, 0);
    __syncthreads();
  }
  // lane: token row = rowA + w*32 + mf*16 + l16; d-cols = df*16 + lh*4 + {0..3}
#pragma unroll
  for (int mf = 0; mf < 2; ++mf) {
    const int tok = rowA + w * 32 + mf * 16 + l16;
    u16* obase = out + ((long)(b << 10) + tok) * 768 + h * 64 + lh * 4;
#pragma unroll
    for (int df = 0; df < 4; ++df) {
      uint2 d;
      d.x = pk2(acc[mf][df][0], acc[mf][df][1]);
      d.y = pk2(acc[mf][df][2], acc[mf][df][3]);
      *(uint2*)(obase + df * 16) = d;
    }
  }
}

// ---------------------------------------------------------------------------
// Depthwise conv1d over tokens, kernel 7, zero pad 3, float4 over channels.
__global__ __launch_bounds__(256) void dwconv4(const float* __restrict__ h2,
                                               const float* __restrict__ wgt,
                                               const float* __restrict__ bias,
                                               float* __restrict__ ct) {
  const int idx = blockIdx.x * 256 + threadIdx.x;  // 4*1024*192
  const int c4 = idx % 192;
  const int n = (idx / 192) % 1024;
  const int b = idx / (192 * 1024);
  const int c = c4 * 4;
  float4 acc = ((const float4*)bias)[c4];
#pragma unroll
  for (int t = 0; t < 7; ++t) {
    const int nn = n + t - 3;
    if (nn >= 0 && nn < 1024) {
      const float4 v = *(const float4*)&h2[((long)(b << 10) + nn) * 768 + c];
      acc.x += v.x * wgt[(c + 0) * 7 + t];
      acc.y += v.y * wgt[(c + 1) * 7 + t];
      acc.z += v.z * wgt[(c + 2) * 7 + t];
      acc.w += v.w * wgt[(c + 3) * 7 + t];
    }
  }
  ((float4*)ct)[idx] = acc;
}

// ---------------------------------------------------------------------------
extern "C" void kernel_launch(void* const* d_in, const int* in_sizes, int n_in,
                              void* d_out, int out_size, void* d_ws, size_t ws_size,
                              hipStream_t stream) {
  const float* x      = (const float*)d_in[0];
  const float* w_qkv  = (const float*)d_in[1];
  const float* b_qkv  = (const float*)d_in[2];
  const float* w_proj = (const float*)d_in[3];
  const float* b_proj = (const float*)d_in[4];
  const float* w_fc1  = (const float*)d_in[5];
  const float* b_fc1  = (const float*)d_in[6];
  const float* w_fc2  = (const float*)d_in[7];
  const float* b_fc2  = (const float*)d_in[8];
  const float* t_bef  = (const float*)d_in[9];
  const float* t_aft  = (const float*)d_in[10];
  const float* g1     = (const float*)d_in[11];
  const float* be1    = (const float*)d_in[12];
  const float* g2     = (const float*)d_in[13];
  const float* be2    = (const float*)d_in[14];
  const float* dw_w   = (const float*)d_in[15];
  const float* dw_b   = (const float*)d_in[16];
  const float* gm     = (const float*)d_in[17];
  const float* bm     = (const float*)d_in[18];
  float* out = (float*)d_out;

  char* wsp = (char*)d_ws;
  size_t off = 0;
  auto alloc = [&](size_t bytes) {
    char* r = wsp + off;
    off += (bytes + 255) & ~(size_t)255;
    return r;
  };
  u16* wqkv_b  = (u16*)alloc((size_t)2304 * 768 * 2);
  u16* wproj_b = (u16*)alloc((size_t)768 * 768 * 2);
  u16* wfc1_b  = (u16*)alloc((size_t)3072 * 768 * 2);
  u16* wfc2_b  = (u16*)alloc((size_t)768 * 3072 * 2);
  u16* h1      = (u16*)alloc((size_t)4096 * 768 * 2);   // LN1 out; dead after QKV
  u16* attn_out = h1;                                   // overlay
  u16* qkvb    = (u16*)alloc((size_t)4096 * 2304 * 2);
  char* attn_region = alloc((size_t)48 * 1024 * 1024 * 2);
  u16* attn = (u16*)attn_region;                        // dead after av_gemm
  size_t ro = 0;
  auto ralloc = [&](size_t bytes) {
    char* r = attn_region + ro;
    ro += (bytes + 255) & ~(size_t)255;
    return r;
  };
  float* x2   = (float*)ralloc((size_t)4096 * 768 * 4);
  float* h2   = (float*)ralloc((size_t)4096 * 768 * 4);
  float* ct   = (float*)ralloc((size_t)4096 * 768 * 4);
  u16*   hm   = (u16*)ralloc((size_t)4096 * 768 * 2);
  u16*   fc1o = (u16*)ralloc((size_t)4096 * 3072 * 2);
  (void)ws_size; (void)n_in; (void)in_sizes; (void)out_size;

  // weight casts (one kernel)
  cast_all<<<6912, 256, 0, stream>>>(w_qkv, w_proj, w_fc1, w_fc2,
                                     wqkv_b, wproj_b, wfc1_b, wfc2_b);
  // LN1
  ln_row<u16><<<4096, 256, 0, stream>>>(x, g1, be1, h1);
  // QKV: [4096,768] @ [2304,768]^T -> [4096,2304]  (128x128 tiles)
  gemm_bt<128, 128, 0, false, u16><<<dim3(18, 32), 256, 0, stream>>>(
      h1, wqkv_b, qkvb, b_qkv, nullptr, 768, 768, 768, 2304, 0);
  // raw per-head scaled scores -> attn
  scores_raw<<<dim3(8, 16, 48), 256, 0, stream>>>(qkvb, attn);
  // fused mix-before + softmax + mix-after (in-place)
  softmax_mix<<<4096, 256, 0, stream>>>(attn, t_bef, t_aft);
  // AV (128-row tiles)
  av_gemm<<<dim3(8, 48), 256, 0, stream>>>(attn, qkvb, attn_out);
  // proj + residual -> x2 (fp32)
  gemm_bt<128, 64, 0, true, float><<<dim3(12, 32), 256, 0, stream>>>(
      attn_out, wproj_b, x2, b_proj, x, 768, 768, 768, 768, 768);
  // LN2 -> h2
  ln_row<float><<<4096, 256, 0, stream>>>(x2, g2, be2, h2);
  // depthwise conv + bias -> ct
  dwconv4<<<3072, 256, 0, stream>>>(h2, dw_w, dw_b, ct);
  // LN mid -> hm (bf16)
  ln_row<u16><<<4096, 256, 0, stream>>>(ct, gm, bm, hm);
  // fc1 + GELU -> fc1o  (128x128 tiles)
  gemm_bt<128, 128, 1, false, u16><<<dim3(24, 32), 256, 0, stream>>>(
      hm, wfc1_b, fc1o, b_fc1, nullptr, 768, 768, 768, 3072, 0);
  // fc2 + residual -> out
  gemm_bt<128, 64, 0, true, float><<<dim3(12, 32), 256, 0, stream>>>(
      fc1o, wfc2_b, out, b_fc2, x2, 3072, 3072, 3072, 768, 768);
}